// Round 4
// baseline (568.227 us; speedup 1.0000x reference)
//
#include <hip/hip_runtime.h>
#include <math.h>

// Problem constants (match reference)
#define B_   16
#define T_   1024
#define F_   512
#define G_   2
#define V_   320
#define D_   128
#define N_   (B_ * T_)      // 16384 tokens
#define GV   (G_ * V_)      // 640
#define EPS_ 1e-7f

// Kernel config
#define ROWS    32          // rows per block
#define THREADS 256         // 4 waves; wave wv owns rows wv*8..wv*8+7
#define KC      128         // k-chunk staged in LDS (16 KB)
#define NBLK    (N_ / ROWS) // 512 blocks

// Workspace layout (floats)
#define WS_COUNTS 0                        // T_*G_*V_ = 655360 (zeroed each launch)
#define WS_AVG    (T_ * G_ * V_)           // NBLK*GV  = 327680
#define WS_ENT    (WS_AVG + NBLK * GV)     // T_*G_    = 2048

#define FMA4(a, xv, wv_)                                                       \
  a = fmaf(xv.x, wv_.x, a); a = fmaf(xv.y, wv_.y, a);                          \
  a = fmaf(xv.z, wv_.z, a); a = fmaf(xv.w, wv_.w, a);

// Fused: GEMM (x @ w^T + b) + softmax stats + argmaxes + codebook gather.
// Thread tile: M=8 rows (wave-uniform LDS broadcast), N=10 cols (5/group x 2).
// NOTE: no min-waves launch_bounds arg — forcing <=128 VGPR would spill
// (~150 live VGPRs) inside the unrolled FMA body.
__global__ __launch_bounds__(THREADS) void k_fused(
    const float* __restrict__ x, const float* __restrict__ w,
    const float* __restrict__ bias, const float* __restrict__ cb,
    const float* __restrict__ gum, float* __restrict__ out,
    float* __restrict__ counts, float* __restrict__ avg_part)
{
  __shared__ float4 xs[ROWS][KC / 4];  // 16 KB; reused for avg-probs reduce
  const int tid = threadIdx.x;
  const int wv  = tid >> 6;   // wave / row-group 0..3
  const int ln  = tid & 63;
  const int blk = blockIdx.x;
  const int n0  = blk * ROWS;
  const int r0  = wv * 8;

  float acc[G_][5][8];
#pragma unroll
  for (int g = 0; g < G_; ++g)
#pragma unroll
    for (int j = 0; j < 5; ++j)
#pragma unroll
      for (int r = 0; r < 8; ++r) acc[g][j][r] = 0.f;

  const float4* w4 = (const float4*)w;
  const float4* x4 = (const float4*)x;

  for (int c = 0; c < F_ / KC; ++c) {  // 4 chunks
    __syncthreads();  // protect previous chunk
    // stage x chunk: 32 rows x 128 k -> 16 KB, coalesced (512 B per row seg)
    for (int i = tid; i < ROWS * (KC / 4); i += THREADS) {
      const int row = i >> 5, kq = i & 31;
      xs[row][kq] = x4[(size_t)(n0 + row) * (F_ / 4) + c * (KC / 4) + kq];
    }
    __syncthreads();

    const int kbase = c * (KC / 4);
#pragma unroll 2
    for (int kk = 0; kk < KC / 4; ++kk) {
      float4 xreg[8];
#pragma unroll
      for (int r = 0; r < 8; ++r) xreg[r] = xs[r0 + r][kk];  // broadcast
#pragma unroll
      for (int g = 0; g < G_; ++g) {
        float4 wreg[5];
#pragma unroll
        for (int j = 0; j < 5; ++j)
          wreg[j] = w4[(size_t)(g * V_ + 64 * j + ln) * (F_ / 4) + kbase + kk];
#pragma unroll
        for (int j = 0; j < 5; ++j)
#pragma unroll
          for (int r = 0; r < 8; ++r) { FMA4(acc[g][j][r], xreg[r], wreg[j]); }
      }
    }
  }

  // ---- phase 2: per-row softmax / argmax / gather, all from registers ----
  float bs[G_][5];
#pragma unroll
  for (int g = 0; g < G_; ++g)
#pragma unroll
    for (int j = 0; j < 5; ++j) bs[g][j] = bias[g * V_ + 64 * j + ln];

  float racc[G_][5];
#pragma unroll
  for (int g = 0; g < G_; ++g)
#pragma unroll
    for (int j = 0; j < 5; ++j) racc[g][j] = 0.f;

#pragma unroll
  for (int r = 0; r < 8; ++r) {
    const int n = n0 + r0 + r;
#pragma unroll
    for (int g = 0; g < G_; ++g) {
      float L[5], GU[5];
#pragma unroll
      for (int j = 0; j < 5; ++j) {
        L[j]  = acc[g][j][r] + bs[g][j];
        GU[j] = gum[(size_t)n * GV + g * V_ + 64 * j + ln];
      }
      // local max/argmax (cols ascend with j -> first-occurrence tie-break)
      float m1 = L[0];         int a1 = ln;
      float m2 = L[0] + GU[0]; int a2 = ln;
#pragma unroll
      for (int j = 1; j < 5; ++j) {
        const int cix = 64 * j + ln;
        if (L[j] > m1) { m1 = L[j]; a1 = cix; }
        const float t2 = L[j] + GU[j];
        if (t2 > m2) { m2 = t2; a2 = cix; }
      }
      // wave reduce (prefer smaller index on exact ties)
      for (int off = 32; off; off >>= 1) {
        float om = __shfl_down(m1, off); int oa = __shfl_down(a1, off);
        if (om > m1 || (om == m1 && oa < a1)) { m1 = om; a1 = oa; }
        float om2 = __shfl_down(m2, off); int oa2 = __shfl_down(a2, off);
        if (om2 > m2 || (om2 == m2 && oa2 < a2)) { m2 = om2; a2 = oa2; }
      }
      m1 = __shfl(m1, 0); a1 = __shfl(a1, 0); a2 = __shfl(a2, 0);

      // softmax (no tau) for avg_probs
      float e[5], s = 0.f;
#pragma unroll
      for (int j = 0; j < 5; ++j) { e[j] = expf(L[j] - m1); s += e[j]; }
      for (int off = 32; off; off >>= 1) s += __shfl_down(s, off);
      s = __shfl(s, 0);
      const float inv = 1.0f / s;
#pragma unroll
      for (int j = 0; j < 5; ++j) racc[g][j] += e[j] * inv;

      if (ln == 0) {
        const int t = n & (T_ - 1);
        atomicAdd(&counts[(t * G_ + g) * V_ + a1], 1.0f);
      }
      // quantized[n, g*D : (g+1)*D] = codebook[g, a2, :]
      const float2* cbr = (const float2*)(cb + (size_t)(g * V_ + a2) * D_);
      float2* op = (float2*)(out + (size_t)n * (G_ * D_) + g * D_);
      op[ln] = cbr[ln];
    }
  }

  // ---- block-level avg_probs partial: reduce 4 wave-private copies ----
  __syncthreads();
  float* la = (float*)xs;  // [4][GV]: 4*640*4B = 10 KB <= 16 KB
#pragma unroll
  for (int g = 0; g < G_; ++g)
#pragma unroll
    for (int j = 0; j < 5; ++j)
      la[wv * GV + g * V_ + 64 * j + ln] = racc[g][j];
  __syncthreads();
  for (int cix = tid; cix < GV; cix += THREADS) {
    float s = 0.f;
#pragma unroll
    for (int v = 0; v < 4; ++v) s += la[v * GV + cix];
    avg_part[(size_t)blk * GV + cix] = s;
  }
}

// Per-(t,g) hard-histogram entropy -> exp(-H). One wave per item.
__global__ __launch_bounds__(256) void k_code_ent(
    const float* __restrict__ counts, float* __restrict__ ent)
{
  const int item = blockIdx.x * 4 + (threadIdx.x >> 6);  // 0..2047
  const int lane = threadIdx.x & 63;
  const float* c = counts + (size_t)item * V_;
  float s = 0.f;
#pragma unroll
  for (int j = 0; j < 5; ++j) {
    const float hp = c[lane + 64 * j] * (1.0f / B_);
    s += hp * logf(hp + EPS_);
  }
  for (int off = 32; off; off >>= 1) s += __shfl_down(s, off);
  if (lane == 0) ent[item] = expf(-s);
}

// Finalize both scalars. Single block of 640 threads.
__global__ __launch_bounds__(GV) void k_final(
    const float* __restrict__ avg_part, const float* __restrict__ ent,
    float* __restrict__ out2)
{
  __shared__ float sh[GV];   // p*log(p+eps) per column
  __shared__ float shc[GV];  // code-entropy partials
  const int tid = threadIdx.x;

  float s = 0.f;
  for (int b = 0; b < NBLK; ++b) s += avg_part[(size_t)b * GV + tid];
  const float p = s * (1.0f / N_);
  sh[tid] = p * logf(p + EPS_);

  float cs = 0.f;
  for (int i = tid; i < T_ * G_; i += GV) cs += ent[i];
  shc[tid] = cs;
  __syncthreads();

  if (tid < 64) {
    float s0 = 0.f, s1 = 0.f, sc = 0.f;
    for (int j = tid; j < V_; j += 64) { s0 += sh[j]; s1 += sh[V_ + j]; }
    for (int j = tid; j < GV; j += 64) sc += shc[j];
    for (int off = 32; off; off >>= 1) {
      s0 += __shfl_down(s0, off);
      s1 += __shfl_down(s1, off);
      sc += __shfl_down(sc, off);
    }
    if (tid == 0) {
      out2[0] = sc;                          // code_perplexity
      out2[1] = expf(-s0) + expf(-s1);       // prob_perplexity
    }
  }
}

extern "C" void kernel_launch(void* const* d_in, const int* in_sizes, int n_in,
                              void* d_out, int out_size, void* d_ws, size_t ws_size,
                              hipStream_t stream) {
  const float* x   = (const float*)d_in[0];  // (B,T,F)
  const float* w   = (const float*)d_in[1];  // (G*V, F)
  const float* b   = (const float*)d_in[2];  // (G*V,)
  const float* cb  = (const float*)d_in[3];  // (1, G*V, D)
  const float* gum = (const float*)d_in[4];  // (B*T, G, V)
  float* out = (float*)d_out;                // quantized (N*G*D) ++ [code_ppl, prob_ppl]
  float* ws  = (float*)d_ws;

  float* counts = ws + WS_COUNTS;
  float* avgp   = ws + WS_AVG;
  float* ent    = ws + WS_ENT;

  hipMemsetAsync(counts, 0, (size_t)T_ * G_ * V_ * sizeof(float), stream);
  k_fused<<<NBLK, THREADS, 0, stream>>>(x, w, b, cb, gum, out, counts, avgp);
  k_code_ent<<<(T_ * G_) / 4, 256, 0, stream>>>(counts, ent);
  k_final<<<1, GV, 0, stream>>>(avgp, ent, out + (size_t)N_ * G_ * D_);
}

// Round 5
// 352.376 us; speedup vs baseline: 1.6126x; 1.6126x over previous
//
#include <hip/hip_runtime.h>
#include <math.h>

// Problem constants (match reference)
#define B_   16
#define T_   1024
#define F_   512
#define G_   2
#define V_   320
#define D_   128
#define N_   (B_ * T_)      // 16384 tokens
#define GV   (G_ * V_)      // 640
#define EPS_ 1e-7f

// Kernel config
#define ROWS    32          // rows per block
#define THREADS 256         // 4 waves; wave wv owns rows wv*8..wv*8+7
#define KC      16          // k-chunk staged in LDS
#define WSTRIDE 20          // padded LDS row stride (floats); 20 = 4 mod 8 -> uniform banks
#define NBLK    (N_ / ROWS) // 512 blocks -> 2 blocks/CU, grid fully resident

// Workspace layout (floats)
#define WS_COUNTS 0                        // T_*G_*V_ = 655360 (zeroed each launch)
#define WS_AVG    (T_ * G_ * V_)           // NBLK*GV  = 327680
#define WS_ENT    (WS_AVG + NBLK * GV)     // T_*G_    = 2048
// avgred (GV floats) reuses counts[0:GV] after k_code_ent has consumed counts.

#define FMA4(a, xv, wv_)                                                       \
  a = fmaf(xv.x, wv_.x, a); a = fmaf(xv.y, wv_.y, a);                          \
  a = fmaf(xv.z, wv_.z, a); a = fmaf(xv.w, wv_.w, a);

// Fused: GEMM (x @ w^T + b) + softmax stats + argmaxes + codebook gather.
// w k-slab staged in LDS once per block (kills the 64-line/inst strided TA
// cost that capped R4 at VALUBusy=26%); x k-slab read as LDS broadcasts.
__global__ __launch_bounds__(THREADS, 2) void k_fused(
    const float* __restrict__ x, const float* __restrict__ w,
    const float* __restrict__ bias, const float* __restrict__ cb,
    const float* __restrict__ gum, float* __restrict__ out,
    float* __restrict__ counts, float* __restrict__ avg_part)
{
  __shared__ float lw[GV][WSTRIDE];    // 50 KB   w k-slab, padded
  __shared__ float lx[ROWS][WSTRIDE];  // 2.5 KB  x k-slab, padded
  const int tid = threadIdx.x;
  const int wv  = tid >> 6;   // wave / row-group 0..3
  const int ln  = tid & 63;
  const int blk = blockIdx.x;
  const int n0  = blk * ROWS;
  const int r0  = wv * 8;

  float acc[G_][5][8];
#pragma unroll
  for (int g = 0; g < G_; ++g)
#pragma unroll
    for (int j = 0; j < 5; ++j)
#pragma unroll
      for (int r = 0; r < 8; ++r) acc[g][j][r] = 0.f;

  const float4* w4 = (const float4*)w;
  const float4* x4 = (const float4*)x;

  for (int c = 0; c < F_ / KC; ++c) {  // 32 chunks
    __syncthreads();  // protect previous chunk
    // stage w k-slab: 640 rows x 16 k. thread i -> (row=i/4, quad=i%4);
    // global: 4 threads cover one 64B row-segment (1 line). 10 iters/thread.
#pragma unroll
    for (int it = 0; it < 10; ++it) {
      const int i = tid + it * THREADS;
      const int row = i >> 2, quad = i & 3;
      *(float4*)&lw[row][quad * 4] = w4[(size_t)row * (F_ / 4) + c * 4 + quad];
    }
    // stage x k-slab: 32 rows x 16 k (threads 0..127)
    if (tid < ROWS * 4) {
      const int row = tid >> 2, quad = tid & 3;
      *(float4*)&lx[row][quad * 4] = x4[(size_t)(n0 + row) * (F_ / 4) + c * 4 + quad];
    }
    __syncthreads();

#pragma unroll
    for (int kk = 0; kk < 4; ++kk) {
      float4 xreg[8];
#pragma unroll
      for (int r = 0; r < 8; ++r)
        xreg[r] = *(const float4*)&lx[r0 + r][kk * 4];  // wave-uniform broadcast
#pragma unroll
      for (int g = 0; g < G_; ++g) {
        float4 wreg[5];
#pragma unroll
        for (int j = 0; j < 5; ++j)
          wreg[j] = *(const float4*)&lw[g * V_ + 64 * j + ln][kk * 4];
#pragma unroll
        for (int j = 0; j < 5; ++j)
#pragma unroll
          for (int r = 0; r < 8; ++r) { FMA4(acc[g][j][r], xreg[r], wreg[j]); }
      }
    }
  }

  // ---- phase 2: per-row softmax / argmax / gather, all from registers ----
  float bs[G_][5];
#pragma unroll
  for (int g = 0; g < G_; ++g)
#pragma unroll
    for (int j = 0; j < 5; ++j) bs[g][j] = bias[g * V_ + 64 * j + ln];

  float racc[G_][5];
#pragma unroll
  for (int g = 0; g < G_; ++g)
#pragma unroll
    for (int j = 0; j < 5; ++j) racc[g][j] = 0.f;

#pragma unroll
  for (int r = 0; r < 8; ++r) {
    const int n = n0 + r0 + r;
#pragma unroll
    for (int g = 0; g < G_; ++g) {
      float L[5], GU[5];
#pragma unroll
      for (int j = 0; j < 5; ++j) {
        L[j]  = acc[g][j][r] + bs[g][j];
        GU[j] = gum[(size_t)n * GV + g * V_ + 64 * j + ln];
      }
      // local max/argmax (cols ascend with j -> first-occurrence tie-break)
      float m1 = L[0];         int a1 = ln;
      float m2 = L[0] + GU[0]; int a2 = ln;
#pragma unroll
      for (int j = 1; j < 5; ++j) {
        const int cix = 64 * j + ln;
        if (L[j] > m1) { m1 = L[j]; a1 = cix; }
        const float t2 = L[j] + GU[j];
        if (t2 > m2) { m2 = t2; a2 = cix; }
      }
      // wave reduce (prefer smaller index on exact ties)
      for (int off = 32; off; off >>= 1) {
        float om = __shfl_down(m1, off); int oa = __shfl_down(a1, off);
        if (om > m1 || (om == m1 && oa < a1)) { m1 = om; a1 = oa; }
        float om2 = __shfl_down(m2, off); int oa2 = __shfl_down(a2, off);
        if (om2 > m2 || (om2 == m2 && oa2 < a2)) { m2 = om2; a2 = oa2; }
      }
      m1 = __shfl(m1, 0); a1 = __shfl(a1, 0); a2 = __shfl(a2, 0);

      // softmax (no tau) for avg_probs
      float e[5], s = 0.f;
#pragma unroll
      for (int j = 0; j < 5; ++j) { e[j] = expf(L[j] - m1); s += e[j]; }
      for (int off = 32; off; off >>= 1) s += __shfl_down(s, off);
      s = __shfl(s, 0);
      const float inv = 1.0f / s;
#pragma unroll
      for (int j = 0; j < 5; ++j) racc[g][j] += e[j] * inv;

      if (ln == 0) {
        const int t = n & (T_ - 1);
        atomicAdd(&counts[(t * G_ + g) * V_ + a1], 1.0f);
      }
      // quantized[n, g*D : (g+1)*D] = codebook[g, a2, :]
      const float2* cbr = (const float2*)(cb + (size_t)(g * V_ + a2) * D_);
      float2* op = (float2*)(out + (size_t)n * (G_ * D_) + g * D_);
      op[ln] = cbr[ln];
    }
  }

  // ---- block-level avg_probs partial: reduce 4 wave-private copies ----
  __syncthreads();
  float* la = (float*)lw;  // [4][GV]: 10240 floats <= 640*20
#pragma unroll
  for (int g = 0; g < G_; ++g)
#pragma unroll
    for (int j = 0; j < 5; ++j)
      la[wv * GV + g * V_ + 64 * j + ln] = racc[g][j];
  __syncthreads();
  for (int cix = tid; cix < GV; cix += THREADS) {
    float s = 0.f;
#pragma unroll
    for (int v = 0; v < 4; ++v) s += la[v * GV + cix];
    avg_part[(size_t)blk * GV + cix] = s;
  }
}

// Per-(t,g) hard-histogram entropy -> exp(-H). One wave per item.
__global__ __launch_bounds__(256) void k_code_ent(
    const float* __restrict__ counts, float* __restrict__ ent)
{
  const int item = blockIdx.x * 4 + (threadIdx.x >> 6);  // 0..2047
  const int lane = threadIdx.x & 63;
  const float* c = counts + (size_t)item * V_;
  float s = 0.f;
#pragma unroll
  for (int j = 0; j < 5; ++j) {
    const float hp = c[lane + 64 * j] * (1.0f / B_);
    s += hp * logf(hp + EPS_);
  }
  for (int off = 32; off; off >>= 1) s += __shfl_down(s, off);
  if (lane == 0) ent[item] = expf(-s);
}

// Column-parallel reduce of avg_part (512 x 640) -> avgred (640).
__global__ __launch_bounds__(64) void k_avg_red(
    const float* __restrict__ avg_part, float* __restrict__ avgred)
{
  const int cix = blockIdx.x;           // 0..639
  const int lane = threadIdx.x;         // 0..63
  float s = 0.f;
  for (int b = lane; b < NBLK; b += 64) s += avg_part[(size_t)b * GV + cix];
  for (int off = 32; off; off >>= 1) s += __shfl_down(s, off);
  if (lane == 0) avgred[cix] = s;
}

// Finalize both scalars. Single block of 640 threads.
__global__ __launch_bounds__(GV) void k_final(
    const float* __restrict__ avgred, const float* __restrict__ ent,
    float* __restrict__ out2)
{
  __shared__ float sh[GV];   // p*log(p+eps) per column
  __shared__ float shc[GV];  // code-entropy partials
  const int tid = threadIdx.x;

  const float p = avgred[tid] * (1.0f / N_);
  sh[tid] = p * logf(p + EPS_);

  float cs = 0.f;
  for (int i = tid; i < T_ * G_; i += GV) cs += ent[i];
  shc[tid] = cs;
  __syncthreads();

  if (tid < 64) {
    float s0 = 0.f, s1 = 0.f, sc = 0.f;
    for (int j = tid; j < V_; j += 64) { s0 += sh[j]; s1 += sh[V_ + j]; }
    for (int j = tid; j < GV; j += 64) sc += shc[j];
    for (int off = 32; off; off >>= 1) {
      s0 += __shfl_down(s0, off);
      s1 += __shfl_down(s1, off);
      sc += __shfl_down(sc, off);
    }
    if (tid == 0) {
      out2[0] = sc;                          // code_perplexity
      out2[1] = expf(-s0) + expf(-s1);       // prob_perplexity
    }
  }
}

extern "C" void kernel_launch(void* const* d_in, const int* in_sizes, int n_in,
                              void* d_out, int out_size, void* d_ws, size_t ws_size,
                              hipStream_t stream) {
  const float* x   = (const float*)d_in[0];  // (B,T,F)
  const float* w   = (const float*)d_in[1];  // (G*V, F)
  const float* b   = (const float*)d_in[2];  // (G*V,)
  const float* cb  = (const float*)d_in[3];  // (1, G*V, D)
  const float* gum = (const float*)d_in[4];  // (B*T, G, V)
  float* out = (float*)d_out;                // quantized (N*G*D) ++ [code_ppl, prob_ppl]
  float* ws  = (float*)d_ws;

  float* counts = ws + WS_COUNTS;
  float* avgp   = ws + WS_AVG;
  float* ent    = ws + WS_ENT;
  float* avgred = counts;  // reuse: counts is dead after k_code_ent (stream-ordered)

  hipMemsetAsync(counts, 0, (size_t)T_ * G_ * V_ * sizeof(float), stream);
  k_fused<<<NBLK, THREADS, 0, stream>>>(x, w, b, cb, gum, out, counts, avgp);
  k_code_ent<<<(T_ * G_) / 4, 256, 0, stream>>>(counts, ent);
  k_avg_red<<<GV, 64, 0, stream>>>(avgp, avgred);
  k_final<<<1, GV, 0, stream>>>(avgred, ent, out + (size_t)N_ * G_ * D_);
}